// Round 6
// baseline (595.646 us; speedup 1.0000x reference)
//
#include <hip/hip_runtime.h>

typedef __attribute__((ext_vector_type(8))) short bf16x8;
typedef __attribute__((ext_vector_type(4))) float f32x4;
typedef __attribute__((ext_vector_type(2))) float f32x2;

static __device__ __forceinline__ unsigned short f2bf(float f) {
    union { float f; unsigned u; } v; v.f = f;
    return (unsigned short)((v.u + 0x7FFFu + ((v.u >> 16) & 1u)) >> 16);
}

// Wp[ch=4][rs=9][oc=256][cw=32] bf16, value = weight[oc][ch*32+cw][r][s] * wscale
__global__ void prep_weights(const float* __restrict__ w, unsigned short* __restrict__ wp) {
    int t = blockIdx.x * 256 + threadIdx.x;      // 0..294911
    const float wscale = 0.02946278254943948f;   // 1/sqrt(3*3*128)
    int cw = t & 31;
    int oc = (t >> 5) & 255;
    int cr = t >> 13;          // 0..35
    int ch = cr / 9;
    int rs = cr - ch * 9;
    int r  = rs / 3;
    int s  = rs - r * 3;
    int c  = ch * 32 + cw;
    wp[t] = f2bf(w[((oc * 128 + c) * 3 + r) * 3 + s] * wscale);
}

// ---- blur helpers ----
#define XROWF(LO, HI, ROW, QP) {                                               \
    int _xr = xr0 + (ROW);                                                     \
    int _xc = _xr < 0 ? 0 : (_xr > 255 ? 255 : _xr);                           \
    const float* _p = (QP) + (_xc << 8);                                       \
    __builtin_memcpy(&LO, _p, 16);                                             \
    __builtin_memcpy(&HI, _p + 4, 8);                                          \
}
#define HROWF(ROW, LO, HI) {                                                   \
    int _xr = xr0 + (ROW);                                                     \
    float _rm = ((unsigned)_xr < 256u) ? 0.125f : 0.0f;                        \
    hA[(ROW) & 3] = (LO.x + 3.f * (LO.y + LO.z) + LO.w) * _rm;                 \
    hB[(ROW) & 3] = (LO.y + 3.f * (LO.z + LO.w) + HI.x) * _rm;                 \
    hC[(ROW) & 3] = (LO.z + 3.f * (LO.w + HI.x) + HI.y) * _rm;                 \
}
#define FROWI(ROW, QP) { f32x4 _lo; f32x2 _hi; XROWF(_lo, _hi, ROW, QP) HROWF(ROW, _lo, _hi) }
#define SROWI(ROW, QP) {                                                       \
    int _xr = xr0 + (ROW);                                                     \
    float w0=0.f,w1=0.f,w2=0.f,w3=0.f,w4=0.f,w5=0.f;                           \
    if ((unsigned)_xr < 256u) {                                                \
        const float* _p = (QP) + (_xr << 8);                                   \
        if ((unsigned)(wc + 0) < 256u) w0 = _p[0];                             \
        if ((unsigned)(wc + 1) < 256u) w1 = _p[1];                             \
        if ((unsigned)(wc + 2) < 256u) w2 = _p[2];                             \
        if ((unsigned)(wc + 3) < 256u) w3 = _p[3];                             \
        if ((unsigned)(wc + 4) < 256u) w4 = _p[4];                             \
        if ((unsigned)(wc + 5) < 256u) w5 = _p[5];                             \
    }                                                                          \
    hA[(ROW) & 3] = (w0 + 3.f * (w1 + w2) + w3) * 0.125f;                      \
    hB[(ROW) & 3] = (w1 + 3.f * (w2 + w3) + w4) * 0.125f;                      \
    hC[(ROW) & 3] = (w2 + 3.f * (w3 + w4) + w5) * 0.125f;                      \
}
#define VROW(ROW, BUFIMM) {                                                    \
    float _b0 = (hA[(ROW-3)&3] + 3.f*(hA[(ROW-2)&3]+hA[(ROW-1)&3]) + hA[(ROW)&3]) * 0.125f; \
    float _b1 = (hB[(ROW-3)&3] + 3.f*(hB[(ROW-2)&3]+hB[(ROW-1)&3]) + hB[(ROW)&3]) * 0.125f; \
    *(unsigned short*)(lds + (BUFIMM) + (ROW-3)*1360 + o0) = f2bf(_b0);        \
    *(unsigned short*)(lds + (BUFIMM) + (ROW-3)*1360 + o1) = f2bf(_b1);        \
    if (a == 7) {                                                              \
        float _b2 = (hC[(ROW-3)&3] + 3.f*(hC[(ROW-2)&3]+hC[(ROW-1)&3]) + hC[(ROW)&3]) * 0.125f; \
        *(unsigned short*)(lds + (BUFIMM) + (ROW-3)*1360 + o2) = f2bf(_b2);    \
    }                                                                          \
}

#define BLURF(QP, QH, BUFIMM, DOH) {                                           \
    float hA[4], hB[4], hC[4];                                                 \
    if (!edge) {                                                               \
        HROWF(0, L0lo, L0hi) HROWF(1, L1lo, L1hi)                              \
        HROWF(2, L2lo, L2hi) HROWF(3, L3lo, L3hi)                              \
        VROW(3, BUFIMM)                                                        \
        FROWI(4, QP)  VROW(4, BUFIMM)   FROWI(5, QP)  VROW(5, BUFIMM)          \
        FROWI(6, QP)  VROW(6, BUFIMM)   FROWI(7, QP)  VROW(7, BUFIMM)          \
        FROWI(8, QP)  VROW(8, BUFIMM)   FROWI(9, QP)  VROW(9, BUFIMM)          \
        FROWI(10, QP) VROW(10, BUFIMM)  FROWI(11, QP) VROW(11, BUFIMM)         \
        FROWI(12, QP) VROW(12, BUFIMM)  FROWI(13, QP) VROW(13, BUFIMM)         \
        FROWI(14, QP) VROW(14, BUFIMM)  FROWI(15, QP) VROW(15, BUFIMM)         \
        FROWI(16, QP) VROW(16, BUFIMM)  FROWI(17, QP) VROW(17, BUFIMM)         \
        FROWI(18, QP) VROW(18, BUFIMM)  FROWI(19, QP) VROW(19, BUFIMM)         \
        if (DOH) {                                                             \
            XROWF(L0lo, L0hi, 0, QH) XROWF(L1lo, L1hi, 1, QH)                  \
            XROWF(L2lo, L2hi, 2, QH) XROWF(L3lo, L3hi, 3, QH)                  \
        }                                                                      \
    } else {                                                                   \
        SROWI(0, QP) SROWI(1, QP) SROWI(2, QP) SROWI(3, QP) VROW(3, BUFIMM)    \
        SROWI(4, QP)  VROW(4, BUFIMM)   SROWI(5, QP)  VROW(5, BUFIMM)          \
        SROWI(6, QP)  VROW(6, BUFIMM)   SROWI(7, QP)  VROW(7, BUFIMM)          \
        SROWI(8, QP)  VROW(8, BUFIMM)   SROWI(9, QP)  VROW(9, BUFIMM)          \
        SROWI(10, QP) VROW(10, BUFIMM)  SROWI(11, QP) VROW(11, BUFIMM)         \
        SROWI(12, QP) VROW(12, BUFIMM)  SROWI(13, QP) VROW(13, BUFIMM)         \
        SROWI(14, QP) VROW(14, BUFIMM)  SROWI(15, QP) VROW(15, BUFIMM)         \
        SROWI(16, QP) VROW(16, BUFIMM)  SROWI(17, QP) VROW(17, BUFIMM)         \
        SROWI(18, QP) VROW(18, BUFIMM)  SROWI(19, QP) VROW(19, BUFIMM)         \
    }                                                                          \
}

#define MF __builtin_amdgcn_mfma_f32_16x16x32_bf16
// one (r,s) step: 4 A-frag ds_reads, 16 MFMAs, prefetch this slot for step+3
#define WSTEP(RR, ADR, BUFIMM, S0, S1, S2, S3) {                               \
    bf16x8 a0 = *(const bf16x8*)(lds + (ADR) + (BUFIMM) + (RR)*1360 +     0);  \
    bf16x8 a1 = *(const bf16x8*)(lds + (ADR) + (BUFIMM) + (RR)*1360 +  5440);  \
    bf16x8 a2 = *(const bf16x8*)(lds + (ADR) + (BUFIMM) + (RR)*1360 + 10880);  \
    bf16x8 a3 = *(const bf16x8*)(lds + (ADR) + (BUFIMM) + (RR)*1360 + 16320);  \
    acc[0][0]=MF(a0,S0,acc[0][0],0,0,0); acc[0][1]=MF(a0,S1,acc[0][1],0,0,0);  \
    acc[0][2]=MF(a0,S2,acc[0][2],0,0,0); acc[0][3]=MF(a0,S3,acc[0][3],0,0,0);  \
    acc[1][0]=MF(a1,S0,acc[1][0],0,0,0); acc[1][1]=MF(a1,S1,acc[1][1],0,0,0);  \
    acc[1][2]=MF(a1,S2,acc[1][2],0,0,0); acc[1][3]=MF(a1,S3,acc[1][3],0,0,0);  \
    acc[2][0]=MF(a2,S0,acc[2][0],0,0,0); acc[2][1]=MF(a2,S1,acc[2][1],0,0,0);  \
    acc[2][2]=MF(a2,S2,acc[2][2],0,0,0); acc[2][3]=MF(a2,S3,acc[2][3],0,0,0);  \
    acc[3][0]=MF(a3,S0,acc[3][0],0,0,0); acc[3][1]=MF(a3,S1,acc[3][1],0,0,0);  \
    acc[3][2]=MF(a3,S2,acc[3][2],0,0,0); acc[3][3]=MF(a3,S3,acc[3][3],0,0,0);  \
    S0 = *(const bf16x8*)(wnx);        S1 = *(const bf16x8*)(wnx + 512);       \
    S2 = *(const bf16x8*)(wnx + 1024); S3 = *(const bf16x8*)(wnx + 1536);      \
    wnx = (wnx < wlast) ? wnx + 8192 : wnx;                                    \
}
#define CHUNK9(BUFIMM)                                                         \
    WSTEP(0, adr0, BUFIMM, PA0, PA1, PA2, PA3)                                 \
    WSTEP(0, adr1, BUFIMM, PB0, PB1, PB2, PB3)                                 \
    WSTEP(0, adr2, BUFIMM, PC0, PC1, PC2, PC3)                                 \
    WSTEP(1, adr0, BUFIMM, PA0, PA1, PA2, PA3)                                 \
    WSTEP(1, adr1, BUFIMM, PB0, PB1, PB2, PB3)                                 \
    WSTEP(1, adr2, BUFIMM, PC0, PC1, PC2, PC3)                                 \
    WSTEP(2, adr0, BUFIMM, PA0, PA1, PA2, PA3)                                 \
    WSTEP(2, adr1, BUFIMM, PB0, PB1, PB2, PB3)                                 \
    WSTEP(2, adr2, BUFIMM, PC0, PC1, PC2, PC3)

// block = 256 thr (4 waves = 4 oc-blocks), tile = 8h x 8w out px x 256 oc.
// LDS: double-buffered blurred tile [17][17] px x 80 B (XOR-swizzled ch slots).
__global__ __launch_bounds__(256, 2)
void conv_blur_mfma(const float* __restrict__ x, const unsigned short* __restrict__ wp,
                    const float* __restrict__ bias, float* __restrict__ out) {
    __shared__ __align__(16) unsigned char lds[2 * 23120];

    // XCD swizzle: the 16 v-tiles of one (n,u0) band share d%8 and are d-adjacent
    const int d    = blockIdx.x;
    const int band = (d & 7) | ((d >> 7) << 3);   // 0..255
    const int n    = band >> 4;
    const int u0   = (band & 15) * 8;
    const int v0   = ((d >> 3) & 15) * 8;

    const int tid  = threadIdx.x;
    const int lane = tid & 63;
    const int wid  = tid >> 6;       // wave = oc-block 0..3
    const int g    = lane >> 4;      // k-group / D-row group
    const int wq   = lane & 15;

    // blur item: channel chl (0..31 in chunk), col-pair a -> blurred cols 2a,2a+1 (+16 if a==7)
    const int a   = tid & 7;
    const int chl = tid >> 3;
    const int wc  = 2 * v0 + 2 * a - 2;
    const bool edge = (v0 == 0 && a == 0) || (v0 == 120 && a == 7);
    const float* pbase = x + (size_t)(n * 128 + chl) * 65536 + wc;
    const int xr0 = 2 * u0 - 2;

    // blur LDS write offsets (row 0)
    const unsigned q4 = (unsigned)(chl >> 3);
    const unsigned cb = (unsigned)(chl & 7) * 2u;
    const int c0 = 2 * a;
    const unsigned o0 = (unsigned)(c0+0)*80u + ((q4 ^ (((unsigned)(c0+0) >> 3) & 3u)) << 4) + cb;
    const unsigned o1 = (unsigned)(c0+1)*80u + ((q4 ^ (((unsigned)(c0+1) >> 3) & 3u)) << 4) + cb;
    const unsigned o2 = (unsigned)(c0+2)*80u + ((q4 ^ (((unsigned)(c0+2) >> 3) & 3u)) << 4) + cb;

    // MFMA A-frag base addrs (per s), row/mf via immediates
    const unsigned hh = (unsigned)(wq >> 3);
    const unsigned rb2h = hh * 2720u;
    const unsigned bj0 = 2u * (unsigned)(wq & 7);
    const unsigned adr0 = rb2h + (bj0+0)*80u + (((unsigned)g ^ (((bj0+0) >> 3) & 3u)) << 4);
    const unsigned adr1 = rb2h + (bj0+1)*80u + (((unsigned)g ^ (((bj0+1) >> 3) & 3u)) << 4);
    const unsigned adr2 = rb2h + (bj0+2)*80u + (((unsigned)g ^ (((bj0+2) >> 3) & 3u)) << 4);

    // weight stream (layout [ch][rs][oc][cw])
    const unsigned short* wbase = wp + (size_t)(wid * 64 + wq) * 32 + g * 8;
    bf16x8 PA0 = *(const bf16x8*)(wbase);
    bf16x8 PA1 = *(const bf16x8*)(wbase + 512);
    bf16x8 PA2 = *(const bf16x8*)(wbase + 1024);
    bf16x8 PA3 = *(const bf16x8*)(wbase + 1536);
    bf16x8 PB0 = *(const bf16x8*)(wbase + 8192);
    bf16x8 PB1 = *(const bf16x8*)(wbase + 8704);
    bf16x8 PB2 = *(const bf16x8*)(wbase + 9216);
    bf16x8 PB3 = *(const bf16x8*)(wbase + 9728);
    bf16x8 PC0 = *(const bf16x8*)(wbase + 16384);
    bf16x8 PC1 = *(const bf16x8*)(wbase + 16896);
    bf16x8 PC2 = *(const bf16x8*)(wbase + 17408);
    bf16x8 PC3 = *(const bf16x8*)(wbase + 17920);
    const unsigned short* wnx   = wbase + 24576;
    const unsigned short* wlast = wbase + 35 * 8192;

    // bias preload
    const float bv0 = bias[wid * 64 +  0 + wq];
    const float bv1 = bias[wid * 64 + 16 + wq];
    const float bv2 = bias[wid * 64 + 32 + wq];
    const float bv3 = bias[wid * 64 + 48 + wq];

    f32x4 acc[4][4];
    #pragma unroll
    for (int i = 0; i < 4; ++i)
        #pragma unroll
        for (int j = 0; j < 4; ++j)
            acc[i][j] = (f32x4){0.f, 0.f, 0.f, 0.f};

    // hoist chunk-0 rows 0..3
    f32x4 L0lo, L1lo, L2lo, L3lo; f32x2 L0hi, L1hi, L2hi, L3hi;
    if (!edge) {
        XROWF(L0lo, L0hi, 0, pbase) XROWF(L1lo, L1hi, 1, pbase)
        XROWF(L2lo, L2hi, 2, pbase) XROWF(L3lo, L3hi, 3, pbase)
    }

    const float* q = pbase;
    #pragma unroll 1
    for (int it = 0; it < 2; ++it) {
        const float* qa = q;
        const float* qb = q + 2097152;
        const float* qc = (it == 0) ? q + 4194304 : qb;  // clamped hoist source
        BLURF(qa, qb, 0, 1)
        __syncthreads();
        CHUNK9(0)
        BLURF(qb, qc, 23120, 1)
        __syncthreads();
        CHUNK9(23120)
        q += 4194304;
    }

    // epilogue: direct stores; D-row m = g*4+i -> u = u0+2mf+(g>>1), v = v0+(g&1)*4+i
    const float gain = 1.4142135623730951f;
    #pragma unroll
    for (int nf = 0; nf < 4; ++nf) {
        const int ocg = wid * 64 + nf * 16 + wq;
        const float bb = (nf == 0) ? bv0 : (nf == 1) ? bv1 : (nf == 2) ? bv2 : bv3;
        #pragma unroll
        for (int mf = 0; mf < 4; ++mf) {
            int u = u0 + 2 * mf + (g >> 1);
            f32x4 o;
            #pragma unroll
            for (int i = 0; i < 4; ++i) {
                float z = acc[mf][nf][i] + bb;
                z = (z >= 0.f ? z : 0.2f * z) * gain;
                o[i] = fminf(fmaxf(z, -256.f), 256.f);
            }
            *(f32x4*)(out + (((size_t)n * 256 + ocg) * 128 + u) * 128 + v0 + (g & 1) * 4) = o;
        }
    }
}

extern "C" void kernel_launch(void* const* d_in, const int* in_sizes, int n_in,
                              void* d_out, int out_size, void* d_ws, size_t ws_size,
                              hipStream_t stream) {
    const float* x    = (const float*)d_in[0];
    const float* w    = (const float*)d_in[1];
    const float* bias = (const float*)d_in[2];
    unsigned short* wp = (unsigned short*)d_ws;   // 589,824 B
    float* out = (float*)d_out;

    prep_weights<<<1152, 256, 0, stream>>>(w, wp);
    conv_blur_mfma<<<4096, 256, 0, stream>>>(x, wp, bias, out);
}